// Round 3
// baseline (616.893 us; speedup 1.0000x reference)
//
#include <hip/hip_runtime.h>
#include <math.h>

#define NN 512
#define RR 262144  // NN*NN
#define EPS_F 1e-5f

typedef unsigned short u16;
typedef unsigned int u32;
typedef __bf16 bf16x8 __attribute__((ext_vector_type(8)));
typedef float f32x4 __attribute__((ext_vector_type(4)));

__device__ __forceinline__ u16 f2bs(float f) {
  __bf16 h = (__bf16)f;
  return __builtin_bit_cast(u16, h);
}
__device__ __forceinline__ float bs2f(u16 u) {
  return (float)__builtin_bit_cast(__bf16, u);
}
__device__ __forceinline__ float sigmoidf_(float x) {
  return 1.f / (1.f + __expf(-x));
}
// async 16B/lane global->LDS. LDS dest = wave-uniform base + lane*16.
__device__ __forceinline__ void async_copy16(const u16* g, u16* l) {
  __builtin_amdgcn_global_load_lds(
      (const __attribute__((address_space(1))) u32*)g,
      (__attribute__((address_space(3))) u32*)l, 16, 0, 0);
}

// ---------------- Kernel W: weight convert + uv precompute ----------------
// wb rows 0..511: ab-interleaved tiles; 512..639: w_g; 640..767: W2=ln_g*w_z.
// uv[0..127]=u[c]=sum_h ln_g[h]*w_z[c,h]; uv[128..255]=v[c]=sum_h ln_b*w_z + b_z.
__global__ __launch_bounds__(256) void k_wconv(
    const float* __restrict__ w_ab_p, const float* __restrict__ w_ab_g,
    const float* __restrict__ w_g, const float* __restrict__ w_z,
    const float* __restrict__ b_z, const float* __restrict__ ln_out_g,
    const float* __restrict__ ln_out_b, u16* __restrict__ wb,
    float* __restrict__ uv) {
  if (blockIdx.x < 96) {
    const int u = blockIdx.x * 256 + threadIdx.x;  // 0..24575
    const int row = u >> 5;                        // 0..767
    const int c4 = (u & 31) * 4;
    float4 v;
    if (row < 512) {
      const int tt = row >> 7, n = row & 127;
      const int srow = tt * 64 + ((n >> 5) << 4) + (n & 15);
      v = *(const float4*)((((n >> 4) & 1) ? w_ab_g : w_ab_p) + srow * 128 + c4);
    } else if (row < 640) {
      v = *(const float4*)(w_g + (row - 512) * 128 + c4);
    } else {
      const int c = row - 640;
      v = *(const float4*)(w_z + c * 128 + c4);
      const float4 gv = *(const float4*)(ln_out_g + c4);
      v.x *= gv.x; v.y *= gv.y; v.z *= gv.z; v.w *= gv.w;
    }
    u16 o[4] = {f2bs(v.x), f2bs(v.y), f2bs(v.z), f2bs(v.w)};
    *(uint2*)(wb + row * 128 + c4) = *(uint2*)o;
  } else {
    const int t = threadIdx.x;
    const int c = t & 127;
    const float* wr = w_z + c * 128;
    float s = 0.f;
    if (t < 128) {
      for (int h = 0; h < 128; ++h) s += ln_out_g[h] * wr[h];
      uv[c] = s;
    } else {
      for (int h = 0; h < 128; ++h) s += ln_out_b[h] * wr[h];
      uv[128 + c] = s + b_z[c];
    }
  }
}

// ---------------- Kernel A: LayerNorm(z) -> zn (bf16, chunk-swizzled) -----
// Row r stores 16B-chunk c at slot (c&8)|((c&7)^(r&7)) for conflict-free
// MFMA frag reads after linear global_load_lds staging in k_proj.
__global__ __launch_bounds__(256) void k_ln_in(const float* __restrict__ z,
                                               const float* __restrict__ g,
                                               const float* __restrict__ b,
                                               u16* __restrict__ zn) {
  const int w = threadIdx.x >> 6, l = threadIdx.x & 63;
  const long r = (long)blockIdx.x * 4 + w;
  const float2 v = *(const float2*)(z + r * 128 + l * 2);
  float s = v.x + v.y, sq = v.x * v.x + v.y * v.y;
#pragma unroll
  for (int m = 1; m < 64; m <<= 1) {
    s += __shfl_xor(s, m);
    sq += __shfl_xor(sq, m);
  }
  const float mu = s * 0.0078125f;
  const float var = sq * 0.0078125f - mu * mu;
  const float rs = rsqrtf(var + EPS_F);
  const float2 gg = *(const float2*)(g + l * 2);
  const float2 bb = *(const float2*)(b + l * 2);
  const u32 o = (u32)f2bs((v.x - mu) * rs * gg.x + bb.x) |
                ((u32)f2bs((v.y - mu) * rs * gg.y + bb.y) << 16);
  const int c = l >> 2;
  const int slot = (c & 8) | ((c & 7) ^ ((int)r & 7));
  *(u32*)(zn + r * 128 + slot * 8 + 2 * (l & 3)) = o;
}

// ---------------- Kernel B: projections ----------------
// grid (2048, 5). zn tile async-staged to LDS; weight frags direct from
// global (L2-hot). tt<4: a/b epilogue with LDS transpose, swizzled store.
__global__ __launch_bounds__(256, 4) void k_proj(
    const u16* __restrict__ zn, const float* __restrict__ mask,
    const u16* __restrict__ wb, const float* __restrict__ b_ab_p,
    const float* __restrict__ b_ab_g, const float* __restrict__ b_g,
    u16* __restrict__ a_t, u16* __restrict__ b_t, u16* __restrict__ g_out) {
  __shared__ __align__(16) u16 As[128 * 128];
  __shared__ float maskS[128];
  const int t = threadIdx.x;
  const int tt = blockIdx.y;
  const long row0 = (long)blockIdx.x * 128;
  const int lane = t & 63, wv = t >> 6;

  {  // async stage zn tile: 32 chunks of 1KB, 8 per wave
#pragma unroll
    for (int q = 0; q < 8; ++q) {
      const int chunk = wv * 8 + q;
      const int row = chunk * 4 + (lane >> 4);
      async_copy16(zn + (row0 + row) * 128 + (lane & 15) * 8, As + chunk * 512);
    }
  }
  if (t < 128) maskS[t] = mask[row0 + t];
  __syncthreads();  // drains vmcnt

  const int quad = lane >> 4, tl = lane & 15;
  const int wm = wv >> 1, wn = wv & 1;
  f32x4 acc[4][4];
#pragma unroll
  for (int mt = 0; mt < 4; ++mt)
#pragma unroll
    for (int nt = 0; nt < 4; ++nt) acc[mt][nt] = (f32x4){0.f, 0.f, 0.f, 0.f};

  const u16* wrow = wb + (long)tt * 128 * 128;
#pragma unroll
  for (int ks = 0; ks < 4; ++ks) {
    bf16x8 af[4], bfr[4];
    const int cA = ks * 4 + quad;
    const int slotA = (cA & 8) | ((cA & 7) ^ (tl & 7));
#pragma unroll
    for (int mt = 0; mt < 4; ++mt)
      af[mt] = *(const bf16x8*)(As + (wm * 64 + mt * 16 + tl) * 128 + slotA * 8);
#pragma unroll
    for (int nt = 0; nt < 4; ++nt)
      bfr[nt] = *(const bf16x8*)(wrow + (wn * 64 + nt * 16 + tl) * 128 + ks * 32 + quad * 8);
#pragma unroll
    for (int mt = 0; mt < 4; ++mt)
#pragma unroll
      for (int nt = 0; nt < 4; ++nt)
        acc[mt][nt] = __builtin_amdgcn_mfma_f32_16x16x32_bf16(af[mt], bfr[nt], acc[mt][nt], 0, 0, 0);
  }

  if (tt < 4) {
    __syncthreads();  // As frag reads done; reuse as transpose buffer
    u16* Ts = As;     // [64 h][stride 136] r
#pragma unroll
    for (int b2 = 0; b2 < 2; ++b2) {
      const int hl = wn * 32 + b2 * 16 + tl;
      const int hg = tt * 64 + hl;
      const float bp = b_ab_p[hg], bg = b_ab_g[hg];
#pragma unroll
      for (int mt = 0; mt < 4; ++mt) {
        u16 pk[4];
#pragma unroll
        for (int rg = 0; rg < 4; ++rg) {
          const int r = wm * 64 + mt * 16 + quad * 4 + rg;
          const float p = acc[mt][2 * b2][rg] + bp;
          const float gt = acc[mt][2 * b2 + 1][rg] + bg;
          pk[rg] = f2bs(sigmoidf_(gt) * maskS[r] * p);
        }
        *(uint2*)(Ts + hl * 136 + wm * 64 + mt * 16 + quad * 4) = *(uint2*)pk;
      }
    }
    __syncthreads();
    {  // swizzled store: chunk cg at slot (cg&56)|((cg&7)^(i&7)) within i-row
      const int hl = t >> 2, qq = t & 3;
      const int hg = tt * 64 + hl;
      u16* dbuf = (tt < 2) ? a_t : b_t;
      const int hb = (tt < 2) ? hg : hg - 128;
      const int i7 = (blockIdx.x >> 2) & 7;          // i & 7
      const int k0c = ((int)row0 & 511) >> 3;        // base chunk (mult of 16)
      const long base = (long)hb * RR + (row0 & ~(long)511);
#pragma unroll
      for (int ii = 0; ii < 4; ++ii) {
        const int lc = qq * 4 + ii;
        const int slot = k0c + (lc & 8) + ((lc & 7) ^ i7);
        *(uint4*)(dbuf + base + slot * 8) = *(const uint4*)(Ts + hl * 136 + lc * 8);
      }
    }
  } else {
#pragma unroll
    for (int nt = 0; nt < 4; ++nt) {
      const int c = wn * 64 + nt * 16 + tl;
      const float bgc = b_g[c];
#pragma unroll
      for (int mt = 0; mt < 4; ++mt)
#pragma unroll
        for (int rg = 0; rg < 4; ++rg) {
          const int r = wm * 64 + mt * 16 + quad * 4 + rg;
          g_out[(row0 + r) * (long)128 + c] = f2bs(sigmoidf_(acc[mt][nt][rg] + bgc));
        }
    }
  }
}

// ---------------- Kernel C: triangle einsum ----------------
// per h: X_h = A_h * B_h^T, 128x128 tile, BK=64, global_load_lds staging.
// a_t/b_t are chunk-swizzled by generator -> frag reads conflict-free.
__global__ __launch_bounds__(256, 4) void k_tri(const u16* __restrict__ a_t,
                                                const u16* __restrict__ b_t,
                                                u16* __restrict__ x_t) {
  __shared__ __align__(16) u16 As[128 * 64];
  __shared__ __align__(16) u16 Bs[128 * 64];
  const int t = threadIdx.x;
  const int h = blockIdx.y;
  const int i0 = (blockIdx.x >> 2) * 128, j0 = (blockIdx.x & 3) * 128;
  const u16* Ag = a_t + (long)h * RR;
  const u16* Bg = b_t + (long)h * RR;
  const int lane = t & 63, wv = t >> 6;
  const int quad = lane >> 4, tl = lane & 15;
  const int wm = wv >> 1, wn = wv & 1;

  f32x4 acc[4][4];
#pragma unroll
  for (int mt = 0; mt < 4; ++mt)
#pragma unroll
    for (int nt = 0; nt < 4; ++nt) acc[mt][nt] = (f32x4){0.f, 0.f, 0.f, 0.f};

  for (int kt = 0; kt < 8; ++kt) {
    __syncthreads();  // prev frag reads done
#pragma unroll
    for (int q = 0; q < 4; ++q) {
      const int chunk = wv * 4 + q;
      const int row = chunk * 8 + (lane >> 3);
      const int kof = kt * 64 + (lane & 7) * 8;
      async_copy16(Ag + (long)(i0 + row) * 512 + kof, As + chunk * 512);
      async_copy16(Bg + (long)(j0 + row) * 512 + kof, Bs + chunk * 512);
    }
    __syncthreads();  // drains vmcnt
#pragma unroll
    for (int ks = 0; ks < 2; ++ks) {
      bf16x8 af[4], bfr[4];
      const int slot = (ks * 4 + quad) ^ (tl & 7);
#pragma unroll
      for (int mt = 0; mt < 4; ++mt)
        af[mt] = *(const bf16x8*)(As + (wm * 64 + mt * 16 + tl) * 64 + slot * 8);
#pragma unroll
      for (int nt = 0; nt < 4; ++nt)
        bfr[nt] = *(const bf16x8*)(Bs + (wn * 64 + nt * 16 + tl) * 64 + slot * 8);
#pragma unroll
      for (int mt = 0; mt < 4; ++mt)
#pragma unroll
        for (int nt = 0; nt < 4; ++nt)
          acc[mt][nt] = __builtin_amdgcn_mfma_f32_16x16x32_bf16(af[mt], bfr[nt], acc[mt][nt], 0, 0, 0);
    }
  }
#pragma unroll
  for (int mt = 0; mt < 4; ++mt)
#pragma unroll
    for (int nt = 0; nt < 4; ++nt)
#pragma unroll
      for (int rg = 0; rg < 4; ++rg) {
        const int i = i0 + wm * 64 + mt * 16 + quad * 4 + rg;
        const int j = j0 + wn * 64 + nt * 16 + tl;
        x_t[(long)h * RR + (long)i * 512 + j] = f2bs(acc[mt][nt][rg]);
      }
}

// ---------------- Kernel D: affine-fused LN(x) @ W2 + gate ----------------
// out = (rs*(x@W2^T - mu*u) + v) * g;  W2 = ln_g*w_z (bf16), u/v precomputed.
__global__ __launch_bounds__(256, 4) void k_out(const u16* __restrict__ x_t,
                                                const u16* __restrict__ w2,
                                                const float* __restrict__ uv,
                                                const u16* __restrict__ g_in,
                                                float* __restrict__ out) {
  __shared__ __align__(16) u16 Xs[128 * 136];
  __shared__ float muS[128], rsS[128];
  const int t = threadIdx.x;
  const long row0 = (long)blockIdx.x * 128;

  {  // stage X transposed: x_t[h][r] -> Xs[r][h], 16B-chunk c rotated by rq*2
    const int hb = t >> 3, rq = t & 7;
    u32 xv[4][8];
#pragma unroll
    for (int hh = 0; hh < 4; ++hh) {
      const uint4* src = (const uint4*)(x_t + (long)(hb * 4 + hh) * RR + row0 + rq * 16);
      const uint4 a = src[0], b = src[1];
      xv[hh][0] = a.x; xv[hh][1] = a.y; xv[hh][2] = a.z; xv[hh][3] = a.w;
      xv[hh][4] = b.x; xv[hh][5] = b.y; xv[hh][6] = b.z; xv[hh][7] = b.w;
    }
    const int cslot0 = (hb >> 1) + rq * 2;
    const int hoff = (hb & 1) * 4;
#pragma unroll
    for (int rr = 0; rr < 16; ++rr) {
      const int row = rq * 16 + rr;
      const int wi = rr >> 1, sh = (rr & 1) * 16;
      const u32 e0 = (xv[0][wi] >> sh) & 0xffffu;
      const u32 e1 = (xv[1][wi] >> sh) & 0xffffu;
      const u32 e2 = (xv[2][wi] >> sh) & 0xffffu;
      const u32 e3 = (xv[3][wi] >> sh) & 0xffffu;
      *(uint2*)(Xs + row * 136 + (cslot0 & 15) * 8 + hoff) =
          make_uint2(e0 | (e1 << 16), e2 | (e3 << 16));
    }
  }
  __syncthreads();
  {  // LN stats only (no write-back); 2 threads/row
    const int r = t >> 1, half = t & 1;
    const int rot = (r >> 4) * 2;
    float s = 0.f, sq = 0.f;
#pragma unroll
    for (int j = 0; j < 8; ++j) {
      const int c = half * 8 + j;
      const bf16x8 v8 = *(const bf16x8*)(Xs + r * 136 + ((c + rot) & 15) * 8);
#pragma unroll
      for (int e = 0; e < 8; ++e) {
        const float v = (float)v8[e];
        s += v;
        sq += v * v;
      }
    }
    s += __shfl_xor(s, 1);
    sq += __shfl_xor(sq, 1);
    if (half == 0) {
      const float mu = s * 0.0078125f;
      const float var = sq * 0.0078125f - mu * mu;
      muS[r] = mu;
      rsS[r] = rsqrtf(var + EPS_F);
    }
  }
  __syncthreads();

  const int lane = t & 63, wv = t >> 6;
  const int quad = lane >> 4, tl = lane & 15;
  const int wm = wv >> 1, wn = wv & 1;
  f32x4 acc[4][4];
#pragma unroll
  for (int mt = 0; mt < 4; ++mt)
#pragma unroll
    for (int nt = 0; nt < 4; ++nt) acc[mt][nt] = (f32x4){0.f, 0.f, 0.f, 0.f};

#pragma unroll
  for (int ks = 0; ks < 4; ++ks) {
    bf16x8 af[4], bfr[4];
    const int c = ks * 4 + quad;
#pragma unroll
    for (int mt = 0; mt < 4; ++mt) {
      const int rot = (wm * 4 + mt) * 2;
      af[mt] = *(const bf16x8*)(Xs + (wm * 64 + mt * 16 + tl) * 136 + ((c + rot) & 15) * 8);
    }
#pragma unroll
    for (int nt = 0; nt < 4; ++nt)
      bfr[nt] = *(const bf16x8*)(w2 + (wn * 64 + nt * 16 + tl) * 128 + ks * 32 + quad * 8);
#pragma unroll
    for (int mt = 0; mt < 4; ++mt)
#pragma unroll
      for (int nt = 0; nt < 4; ++nt)
        acc[mt][nt] = __builtin_amdgcn_mfma_f32_16x16x32_bf16(af[mt], bfr[nt], acc[mt][nt], 0, 0, 0);
  }
#pragma unroll
  for (int nt = 0; nt < 4; ++nt) {
    const int c = wn * 64 + nt * 16 + tl;
    const float uc = uv[c], vc = uv[128 + c];
#pragma unroll
    for (int mt = 0; mt < 4; ++mt)
#pragma unroll
      for (int rg = 0; rg < 4; ++rg) {
        const int r = wm * 64 + mt * 16 + quad * 4 + rg;
        const long idx = (row0 + r) * 128 + c;
        out[idx] = (rsS[r] * (acc[mt][nt][rg] - muS[r] * uc) + vc) * bs2f(g_in[idx]);
      }
  }
}

extern "C" void kernel_launch(void* const* d_in, const int* in_sizes, int n_in,
                              void* d_out, int out_size, void* d_ws, size_t ws_size,
                              hipStream_t stream) {
  const float* z = (const float*)d_in[0];
  const float* mask = (const float*)d_in[1];
  const float* w_ab_p = (const float*)d_in[2];
  const float* b_ab_p = (const float*)d_in[3];
  const float* w_ab_g = (const float*)d_in[4];
  const float* b_ab_g = (const float*)d_in[5];
  const float* w_g = (const float*)d_in[6];
  const float* b_g = (const float*)d_in[7];
  const float* w_z = (const float*)d_in[8];
  const float* b_z = (const float*)d_in[9];
  const float* ln_in_g = (const float*)d_in[10];
  const float* ln_in_b = (const float*)d_in[11];
  const float* ln_out_g = (const float*)d_in[12];
  const float* ln_out_b = (const float*)d_in[13];
  float* out = (float*)d_out;

  // workspace: zn, a_t, b_t, x_t, g (5 * 64 MB u16) + wb (192 KB) + uv (1 KB)
  u16* zn = (u16*)d_ws;
  u16* a_t = zn + (size_t)RR * 128;
  u16* b_t = a_t + (size_t)RR * 128;
  u16* x_t = b_t + (size_t)RR * 128;
  u16* g_b = x_t + (size_t)RR * 128;
  u16* wb = g_b + (size_t)RR * 128;
  float* uv = (float*)(wb + 768 * 128);

  k_wconv<<<97, 256, 0, stream>>>(w_ab_p, w_ab_g, w_g, w_z, b_z, ln_out_g,
                                  ln_out_b, wb, uv);
  k_ln_in<<<RR / 4, 256, 0, stream>>>(z, ln_in_g, ln_in_b, zn);
  k_proj<<<dim3(RR / 128, 5), 256, 0, stream>>>(zn, mask, wb, b_ab_p, b_ab_g,
                                                b_g, a_t, b_t, g_b);
  k_tri<<<dim3(16, 128), 256, 0, stream>>>(a_t, b_t, x_t);
  k_out<<<RR / 128, 256, 0, stream>>>(x_t, wb + 640 * 128, uv, g_b, out);
}